// Round 5
// baseline (347.078 us; speedup 1.0000x reference)
//
#include <hip/hip_runtime.h>

// ProtoNet: out[q][n] = -|| (xq[q]@W + b) - proto[n] ||^2
// v5: TLP fix. k3 = 64x128 tile, 4 waves (each 32x64), grid 1024 = 4 blk/CU
// x 4 waves = 16 waves/CU (was 8). Single-buffer 2-barrier loop (dbuf was
// measured-neutral). Fused distance epilogue unchanged in semantics.
//   k_prep : transpose W -> Wt bf16; zero out + pnorm_part; bin ys
//   k1_csum: per-class support sums (f32)            -> csum [64][2048]
//   k2_full: proto = csum@W/cnt + b in one shot      -> proto_bf + pnorm_part
//   k3_fused: z = xq@W + b (64x128 tile) + per-128-slice distance epilogue,
//             atomicAdd into pre-zeroed out.

typedef __attribute__((ext_vector_type(8))) short short8;
typedef __attribute__((ext_vector_type(4))) float floatx4;

#define S_ROWS 1024
#define F_DIM  2048
#define D_DIM  512
#define NWAY   64
#define Q_ROWS 16384
#define ZS_LD  136

static __device__ __forceinline__ unsigned short f2bf(float f) {
  unsigned int u = __float_as_uint(f);
  u += 0x7FFF + ((u >> 16) & 1);   // RNE
  return (unsigned short)(u >> 16);
}
static __device__ __forceinline__ float bf2f(unsigned short s) {
  return __uint_as_float(((unsigned int)s) << 16);
}
// pack two floats -> two bf16 (round-half-up; ties-only deviation from RNE)
static __device__ __forceinline__ unsigned int pack_bf2(float x, float y) {
  unsigned int ux = __float_as_uint(x) + 0x8000u;
  unsigned int uy = __float_as_uint(y) + 0x8000u;
  return __builtin_amdgcn_perm(uy, ux, 0x07060302u);  // hi16(uy)<<16 | hi16(ux)
}
// async global->LDS, 16B per lane. LDS dest = wave-uniform base + lane*16.
static __device__ __forceinline__ void load_lds16(const unsigned short* g, unsigned short* l) {
  __builtin_amdgcn_global_load_lds((const __attribute__((address_space(1))) unsigned int*)g,
                                   (__attribute__((address_space(3))) unsigned int*)l,
                                   16, 0, 0);
}

// ---- k_prep: blocks 0..255 transpose W + zero their slice of out;
//      block 256 bins support ids by class + zeroes pnorm_part ----
__global__ __launch_bounds__(256) void k_prep(const float* __restrict__ W,
                                              unsigned short* __restrict__ Wt,
                                              float* __restrict__ outz,
                                              float* __restrict__ pnorm_part,
                                              const int* __restrict__ ys,
                                              int* __restrict__ order,
                                              int* __restrict__ starts,
                                              float* __restrict__ counts) {
  __shared__ unsigned short t[64][65];
  __shared__ int cnt[NWAY];
  __shared__ int st[NWAY + 1];
  __shared__ int wp[NWAY];
  int bx = blockIdx.x;
  int tid = threadIdx.x;
  if (bx < 256) {
    // zero this block's slice of out (16384*64 f32 total)
    float4 zz = {0.f, 0.f, 0.f, 0.f};
#pragma unroll
    for (int p = 0; p < 4; p++)
      *(float4*)&outz[(size_t)bx * 4096 + p * 1024 + tid * 4] = zz;
    int f0 = (bx >> 3) << 6;   // 32 f-tiles
    int d0 = (bx & 7) << 6;    // 8 d-tiles
    for (int j = 0; j < 16; j++) {
      int lin = j * 256 + tid;
      int fl = lin >> 6, dl = lin & 63;
      t[fl][dl] = f2bf(W[(size_t)(f0 + fl) * D_DIM + d0 + dl]);
    }
    __syncthreads();
    for (int j = 0; j < 16; j++) {
      int lin = j * 256 + tid;
      int dl = lin >> 6, fl = lin & 63;
      Wt[(size_t)(d0 + dl) * F_DIM + f0 + fl] = t[fl][dl];
    }
  } else {
    pnorm_part[tid] = 0.f;   // 256 entries = [4 slices][64 classes]
    if (tid < NWAY) cnt[tid] = 0;
    __syncthreads();
    for (int j = tid; j < S_ROWS; j += 256) atomicAdd(&cnt[ys[j]], 1);
    __syncthreads();
    if (tid == 0) {
      int a = 0;
      for (int c = 0; c < NWAY; c++) { st[c] = a; wp[c] = a; a += cnt[c]; }
      st[NWAY] = a;
    }
    __syncthreads();
    for (int j = tid; j < S_ROWS; j += 256) {
      int c = ys[j];
      int p = atomicAdd(&wp[c], 1);
      order[p] = j;
    }
    if (tid < NWAY) counts[tid] = (float)cnt[tid];
    if (tid < NWAY + 1) starts[tid] = st[tid];
  }
}

// ---- K1: class sums. grid = 64 classes x 2 f-tiles; float4 per thread ----
__global__ __launch_bounds__(256) void k1_csum(const float* __restrict__ xs,
                                               const int* __restrict__ order,
                                               const int* __restrict__ starts,
                                               float* __restrict__ csum) {
  __shared__ int lord[S_ROWS];
  int c = blockIdx.x >> 1;
  int tid = threadIdx.x;
  int s = starts[c], e = starts[c + 1];
  int len = e - s;
  for (int j = tid; j < len; j += 256) lord[j] = order[s + j];
  __syncthreads();
  int f0 = (blockIdx.x & 1) * 1024 + tid * 4;
  float4 a = {0.f, 0.f, 0.f, 0.f};
  for (int i = 0; i < len; i++) {
    float4 v = *(const float4*)&xs[(size_t)lord[i] * F_DIM + f0];
    a.x += v.x; a.y += v.y; a.z += v.z; a.w += v.w;
  }
  *(float4*)&csum[(size_t)c * F_DIM + f0] = a;
}

// ---- k2_full: proto in one shot. grid = 8 class-groups x 8 d-chunks = 64.
//      Block: 8 classes x 64 d cols, full K=2048 via 32 LDS-staged chunks.
//      Writes proto_bf + atomicAdd per-slice pnorm_part. ----
__global__ __launch_bounds__(256) void k2_full(const float* __restrict__ W,
                                               const float* __restrict__ csum,
                                               const float* __restrict__ b,
                                               const float* __restrict__ counts,
                                               unsigned short* __restrict__ proto_bf,
                                               float* __restrict__ pnorm_part) {
  __shared__ __align__(16) float wch[64 * 64];   // 16 KB
  __shared__ float csl[8 * 64];                  // 2 KB
  int bx = blockIdx.x;
  int cg = bx >> 3, dc = bx & 7;
  int c0 = cg * 8, d0 = dc * 64;
  int tid = threadIdx.x;
  int cl = tid >> 5;          // local class 0..7
  int dl = (tid & 31) * 2;    // local d col pair
  float a0 = 0.f, a1 = 0.f;
  for (int fs = 0; fs < 32; fs++) {
    int f0 = fs * 64;
    __syncthreads();
    for (int idx = tid; idx < 4096; idx += 256) {
      int r = idx >> 6, q = idx & 63;
      wch[idx] = W[(size_t)(f0 + r) * D_DIM + d0 + q];
    }
    for (int idx = tid; idx < 512; idx += 256) {
      int r = idx >> 6, q = idx & 63;
      csl[idx] = csum[(size_t)(c0 + r) * F_DIM + f0 + q];
    }
    __syncthreads();
#pragma unroll 8
    for (int f = 0; f < 64; f++) {
      float s = csl[cl * 64 + f];
      a0 += s * wch[f * 64 + dl];
      a1 += s * wch[f * 64 + dl + 1];
    }
  }
  int c = c0 + cl;
  float cntv = counts[c];
  float inv = 1.f / fmaxf(cntv, 1.f);
  float p0 = (a0 + cntv * b[d0 + dl]) * inv;     // cnt==0 -> 0, matches ref
  float p1 = (a1 + cntv * b[d0 + dl + 1]) * inv;
  unsigned short h0 = f2bf(p0), h1 = f2bf(p1);
  proto_bf[(size_t)c * D_DIM + d0 + dl] = h0;
  proto_bf[(size_t)c * D_DIM + d0 + dl + 1] = h1;
  float q0 = bf2f(h0), q1 = bf2f(h1);
  float s2 = q0 * q0 + q1 * q1;
  s2 += __shfl_xor(s2, 1, 32);
  s2 += __shfl_xor(s2, 2, 32);
  s2 += __shfl_xor(s2, 4, 32);
  s2 += __shfl_xor(s2, 8, 32);
  s2 += __shfl_xor(s2, 16, 32);
  if ((tid & 31) == 0) atomicAdd(&pnorm_part[(dc >> 1) * 64 + c], s2);
}

// ---- k3_fused: 64x128 z-tile GEMM (4 waves, each 32x64; single-buffer,
//      2 barriers/K-step) + fused distance epilogue.
//      grid = 256 m-tiles x 4 n-slices = 1024 blocks -> 16 waves/CU. ----
__global__ __launch_bounds__(256, 4) void k3_fused(const float* __restrict__ xq,
                                                   const unsigned short* __restrict__ Wt,
                                                   const float* __restrict__ b,
                                                   const unsigned short* __restrict__ proto_bf,
                                                   const float* __restrict__ pnorm_part,
                                                   float* __restrict__ out) {
  // LDS: main loop lA(8K f32->bf16) + lB(16K) = 24K; epilogue overlays
  // zs (64 x ZS_LD halfs = 17408B) on the same region; qnf/pnl at tail.
  __shared__ __align__(16) char smem[25088];
  unsigned short* lA = (unsigned short*)smem;            // [64][64] halfs
  unsigned short* lB = (unsigned short*)(smem + 8192);   // [128][64] halfs
  unsigned short* zs = (unsigned short*)smem;            // [64][ZS_LD] halfs
  float* qnf = (float*)(smem + 24576);                   // 64
  float* pnl = (float*)(smem + 24832);                   // 64

  int tid = threadIdx.x;
  int bx = blockIdx.x;
  // XCD swizzle (1024 % 8 == 0, bijective): 4 n-slices of one m-tile are
  // dispatch-neighbors on the same XCD -> L2 reuse of xq.
  int xcd = bx & 7;
  int wg = xcd * 128 + (bx >> 3);
  int mt = wg >> 2;                 // 0..255
  int slice = wg & 3;
  int n0 = slice * 128;

  int wave = tid >> 6, lane = tid & 63;
  int wm = wave >> 1, wn = wave & 1;   // wave-grid 2m x 2n; wave tile 32x64
  int lrow = lane & 15, lquad = lane >> 4;

  const float* Ab = xq + (size_t)mt * 64 * F_DIM;

  floatx4 acc[2][4];
#pragma unroll
  for (int i = 0; i < 2; i++)
#pragma unroll
    for (int j = 0; j < 4; j++) acc[i][j] = (floatx4){0.f, 0.f, 0.f, 0.f};

  // A staging: 64 rows x 64 cols f32 -> bf16. thread: row=tid>>2, 16 cols.
  int arow = tid >> 2, akq = tid & 3;
  const float* ag = Ab + (size_t)arow * F_DIM + akq * 16;
  unsigned short* aw = &lA[arow * 64 + akq * 16];
  // B staging: [128][64] halfs via DMA, chunk ch=i*256+tid (verified r2 map):
  // row = i*32 + (tid>>3), kq = tid&7.
  const unsigned short* bg = Wt + (size_t)(n0 + (tid >> 3)) * F_DIM + (tid & 7) * 8;

  for (int k0 = 0; k0 < F_DIM; k0 += 64) {
    // B: async global->LDS (issue first; DMA overlaps A's VGPR path)
#pragma unroll
    for (int i = 0; i < 4; i++)
      load_lds16(bg + (size_t)i * 32 * F_DIM + k0, &lB[(i * 256 + wave * 64) * 8]);
    // A: f32 global -> regs -> pack bf16 -> LDS
    {
      const float* gp = ag + k0;
      float4 v0 = *(const float4*)gp;
      float4 v1 = *(const float4*)(gp + 4);
      float4 v2 = *(const float4*)(gp + 8);
      float4 v3 = *(const float4*)(gp + 12);
      uint4 w0, w1;
      w0.x = pack_bf2(v0.x, v0.y); w0.y = pack_bf2(v0.z, v0.w);
      w0.z = pack_bf2(v1.x, v1.y); w0.w = pack_bf2(v1.z, v1.w);
      w1.x = pack_bf2(v2.x, v2.y); w1.y = pack_bf2(v2.z, v2.w);
      w1.z = pack_bf2(v3.x, v3.y); w1.w = pack_bf2(v3.z, v3.w);
      *(uint4*)aw = w0;
      *(uint4*)(aw + 8) = w1;
    }
    __syncthreads();
#pragma unroll
    for (int s = 0; s < 2; s++) {
      short8 af[2], bfr[4];
#pragma unroll
      for (int i = 0; i < 2; i++)
        af[i] = *(const short8*)&lA[(wm * 32 + i * 16 + lrow) * 64 + s * 32 + lquad * 8];
#pragma unroll
      for (int j = 0; j < 4; j++)
        bfr[j] = *(const short8*)&lB[(wn * 64 + j * 16 + lrow) * 64 + s * 32 + lquad * 8];
#pragma unroll
      for (int i = 0; i < 2; i++)
#pragma unroll
        for (int j = 0; j < 4; j++)
          acc[i][j] = __builtin_amdgcn_mfma_f32_16x16x32_bf16(af[i], bfr[j], acc[i][j], 0, 0, 0);
    }
    __syncthreads();
  }

  // ---- epilogue A: init qn accumulator + load per-slice proto norms ----
  if (tid < 64) { qnf[tid] = 0.f; pnl[tid] = pnorm_part[slice * 64 + tid]; }
  __syncthreads();

  // ---- epilogue B: z -> LDS bf16 (64 x 128) + per-row slice norms ----
#pragma unroll
  for (int i = 0; i < 2; i++) {
    float rn[4] = {0.f, 0.f, 0.f, 0.f};
#pragma unroll
    for (int j = 0; j < 4; j++) {
      int col = wn * 64 + j * 16 + lrow;              // local d (0..127)
      float bb = b[n0 + col];
#pragma unroll
      for (int r = 0; r < 4; r++) {
        int row = wm * 32 + i * 16 + lquad * 4 + r;   // local q (0..63)
        float v = acc[i][j][r] + bb;
        unsigned short h = f2bf(v);
        zs[row * ZS_LD + col] = h;
        float vq = bf2f(h);
        rn[r] += vq * vq;
      }
    }
#pragma unroll
    for (int r = 0; r < 4; r++) {
      float s2 = rn[r];
      s2 += __shfl_xor(s2, 1, 16);
      s2 += __shfl_xor(s2, 2, 16);
      s2 += __shfl_xor(s2, 4, 16);
      s2 += __shfl_xor(s2, 8, 16);
      if (lrow == 0) atomicAdd(&qnf[wm * 32 + i * 16 + lquad * 4 + r], s2);
    }
  }
  __syncthreads();

  // ---- epilogue C: S = zs(64x128) @ proto_slice(64x128)^T. Each wave owns
  //      16 q-rows over full K=128. proto B-frags from global (L2-hot). ----
  floatx4 acc2[4];
#pragma unroll
  for (int j = 0; j < 4; j++) acc2[j] = (floatx4){0.f, 0.f, 0.f, 0.f};

#pragma unroll
  for (int ks = 0; ks < 4; ks++) {
    short8 af2 = *(const short8*)&zs[(wave * 16 + lrow) * ZS_LD + ks * 32 + lquad * 8];
#pragma unroll
    for (int j = 0; j < 4; j++) {
      short8 bp = *(const short8*)&proto_bf[(size_t)(j * 16 + lrow) * D_DIM + n0 + ks * 32 + lquad * 8];
      acc2[j] = __builtin_amdgcn_mfma_f32_16x16x32_bf16(af2, bp, acc2[j], 0, 0, 0);
    }
  }

  // ---- epilogue D: out += 2S - qn_slice - pn_slice ----
  size_t qbase = (size_t)mt * 64;
#pragma unroll
  for (int j = 0; j < 4; j++) {
    int c = j * 16 + lrow;
    float pn = pnl[c];
#pragma unroll
    for (int r = 0; r < 4; r++) {
      int ql = wave * 16 + lquad * 4 + r;
      float val = 2.f * acc2[j][r] - qnf[ql] - pn;
      atomicAdd(&out[(qbase + ql) * NWAY + c], val);
    }
  }
}

extern "C" void kernel_launch(void* const* d_in, const int* in_sizes, int n_in,
                              void* d_out, int out_size, void* d_ws, size_t ws_size,
                              hipStream_t stream) {
  const float* xs = (const float*)d_in[0];
  const int* ys = (const int*)d_in[1];
  const float* xq = (const float*)d_in[2];
  const float* W = (const float*)d_in[3];
  const float* b = (const float*)d_in[4];
  float* out = (float*)d_out;
  char* ws = (char*)d_ws;

  size_t off = 0;
  auto take = [&](size_t bytes) -> char* {
    char* r = ws + off;
    off += (bytes + 255) & ~(size_t)255;
    return r;
  };
  unsigned short* Wt = (unsigned short*)take((size_t)D_DIM * F_DIM * 2);       // 2 MB
  float* csum = (float*)take((size_t)NWAY * F_DIM * 4);                        // 512 KB
  unsigned short* proto_bf = (unsigned short*)take((size_t)NWAY * D_DIM * 2);  // 64 KB
  float* counts = (float*)take(NWAY * 4);
  float* pnorm_part = (float*)take(4 * NWAY * 4);
  int* order = (int*)take(S_ROWS * 4);
  int* starts = (int*)take((NWAY + 1) * 4);

  // Workspace guard: fail cleanly rather than corrupt device memory.
  if (off > ws_size) return;

  k_prep<<<257, 256, 0, stream>>>(W, Wt, out, pnorm_part, ys, order, starts, counts);
  k1_csum<<<128, 256, 0, stream>>>(xs, order, starts, csum);
  k2_full<<<64, 256, 0, stream>>>(W, csum, b, counts, proto_bf, pnorm_part);
  k3_fused<<<1024, 256, 0, stream>>>(xq, Wt, b, proto_bf, pnorm_part, out);
}